// Round 14
// baseline (229.043 us; speedup 1.0000x reference)
//
#include <hip/hip_runtime.h>
#include <hip/hip_bf16.h>
#include <stdint.h>

typedef unsigned short u16;
typedef __attribute__((ext_vector_type(8))) short short8;
typedef __attribute__((ext_vector_type(4))) float f32x4;

__device__ __forceinline__ float bf2f(u16 u) {
    union { uint32_t u; float f; } v; v.u = ((uint32_t)u) << 16; return v.f;
}
__device__ __forceinline__ u16 f2bf(float f) {
    union { float f; uint32_t u; } v; v.f = f;
    uint32_t r = (v.u + 0x7fffu + ((v.u >> 16) & 1u)) >> 16;
    return (u16)r;
}
__device__ __forceinline__ uint32_t pkbf(float a, float b) {
    union { __hip_bfloat162 h; uint32_t w; } u;
    u.h = __float22bfloat162_rn(float2{a, b});
    return u.w;
}
__device__ __forceinline__ void store_out(u16* p, float v) { *p = f2bf(v); }
__device__ __forceinline__ void store_out(float* p, float v) { *p = v; }

__device__ __forceinline__ void async_ld16(const u16* g, u16* l) {
    __builtin_amdgcn_global_load_lds(
        (const __attribute__((address_space(1))) void*)g,
        (__attribute__((address_space(3))) void*)l, 16, 0, 0);
}

// ---------------------------------------------------------------------------
// prep: z in {0,1,2} -> transpose wq/wk/wv fp32 -> bf16 wT[z];
//       z in {3,4}   -> cvt x fp32 -> bf16 (chunk z-3 of 2);
//       z == 5       -> transpose wo -> woT (fused path only).
// ---------------------------------------------------------------------------
__global__ void prep(const float* __restrict__ x,
                     const float* __restrict__ w0, const float* __restrict__ w1,
                     const float* __restrict__ w2, const float* __restrict__ w3,
                     u16* __restrict__ xb, u16* __restrict__ wT,
                     u16* __restrict__ woT) {
    const int z = blockIdx.z;
    __shared__ u16 tile[32][33];
    if (z == 3 || z == 4) {
        int blk = (z - 3) * 1024 + blockIdx.y * 32 + blockIdx.x;
        int tid = threadIdx.y * 32 + threadIdx.x;
        int i = (blk * 256 + tid) * 8;
        float4 a = *(const float4*)(x + i);
        float4 b = *(const float4*)(x + i + 4);
        union { uint32_t w[4]; uint4 v; } o;
        o.w[0] = pkbf(a.x, a.y); o.w[1] = pkbf(a.z, a.w);
        o.w[2] = pkbf(b.x, b.y); o.w[3] = pkbf(b.z, b.w);
        *(uint4*)(xb + i) = o.v;
        return;
    }
    const float* in = (z == 0) ? w0 : (z == 1) ? w1 : (z == 2) ? w2 : w3;
    u16* o = (z < 3) ? (wT + (size_t)z * 1024 * 1024) : woT;
    int xx = blockIdx.x * 32 + threadIdx.x;
    int y0 = blockIdx.y * 32;
#pragma unroll
    for (int j = threadIdx.y; j < 32; j += 8)
        tile[j][threadIdx.x] = f2bf(in[(size_t)(y0 + j) * 1024 + xx]);
    __syncthreads();
    int ox = blockIdx.y * 32 + threadIdx.x;
    int oy0 = blockIdx.x * 32;
#pragma unroll
    for (int j = threadIdx.y; j < 32; j += 8)
        o[(size_t)(oy0 + j) * 1024 + ox] = tile[threadIdx.x][j];
}

// single-plane weight transpose (fallback path when workspace is tight)
__global__ void transpose1(const float* __restrict__ w, u16* __restrict__ out) {
    __shared__ u16 tile[32][33];
    int x = blockIdx.x * 32 + threadIdx.x;
    int y0 = blockIdx.y * 32;
#pragma unroll
    for (int j = threadIdx.y; j < 32; j += 8)
        tile[j][threadIdx.x] = f2bf(w[(size_t)(y0 + j) * 1024 + x]);
    __syncthreads();
    int ox = blockIdx.y * 32 + threadIdx.x;
    int oy0 = blockIdx.x * 32;
#pragma unroll
    for (int j = threadIdx.y; j < 32; j += 8)
        out[(size_t)(oy0 + j) * 1024 + ox] = tile[threadIdx.x][j];
}

// ---------------------------------------------------------------------------
// GEMM (B^T bf16): double-buffered async-LDS staging, ONE barrier per K-iter.
// 128x128 tile, 4 waves in 2x2.  XCD-chunked 2D block swizzle (measured win).
// ---------------------------------------------------------------------------
#define GBM 128
#define GBN 128
#define GBK 32

template <typename OutT>
__global__ __launch_bounds__(256) void gemm_bt(
    const u16* __restrict__ A, int lda,
    const u16* __restrict__ BT, int ldb,
    const float* __restrict__ bias0, const float* __restrict__ bias1,
    const float* __restrict__ bias2,
    OutT* __restrict__ C, int ldc, int K) {
    __shared__ __align__(16) u16 As[2][GBM * GBK];
    __shared__ __align__(16) u16 Bs[2][GBN * GBK];

    const int tid = threadIdx.x;
    const int wave = tid >> 6, lane = tid & 63;
    const int quad = lane >> 4, l16 = lane & 15;
    const int wr = wave >> 1, wc = wave & 1;

    int bx = blockIdx.x, by = blockIdx.y;
    if (gridDim.x == 24 && gridDim.y == 32) {
        const int wgid = blockIdx.x + blockIdx.y * 24;
        const int xcd = wgid & 7, t = wgid >> 3;      // t: 0..95
        bx = (xcd & 1) * 12 + t % 12;
        by = (xcd >> 1) * 8 + t / 12;
    }
    const int m0 = by * GBM, n0 = bx * GBN;

    const int seg = n0 >> 10;
    const float* bsel = (seg == 0) ? bias0 : (seg == 1) ? bias1 : bias2;

    f32x4 acc[4][4] = {};

    const int srow = tid >> 2;
    const int scol = (tid & 3) * 8;
    const u16* Ag0 = A + (size_t)(m0 + srow) * lda + scol;
    const u16* Ag1 = Ag0 + (size_t)64 * lda;
    const u16* Bg0 = BT + (size_t)(n0 + srow) * ldb + scol;
    const u16* Bg1 = Bg0 + (size_t)64 * ldb;
    const int woff = wave << 9;

    async_ld16(Ag0, As[0] + woff);
    async_ld16(Ag1, As[0] + woff + 64 * GBK);
    async_ld16(Bg0, Bs[0] + woff);
    async_ld16(Bg1, Bs[0] + woff + 64 * GBK);

    int cur = 0;
    for (int kb = 0; kb < K; kb += GBK) {
        __syncthreads();

        if (kb + GBK < K) {
            const int nxt = cur ^ 1;
            async_ld16(Ag0 + kb + GBK, As[nxt] + woff);
            async_ld16(Ag1 + kb + GBK, As[nxt] + woff + 64 * GBK);
            async_ld16(Bg0 + kb + GBK, Bs[nxt] + woff);
            async_ld16(Bg1 + kb + GBK, Bs[nxt] + woff + 64 * GBK);
        }

        short8 af[4], bf[4];
#pragma unroll
        for (int mt = 0; mt < 4; mt++)
            af[mt] = *(const short8*)(As[cur] + (wr * 64 + mt * 16 + l16) * GBK + quad * 8);
#pragma unroll
        for (int nt = 0; nt < 4; nt++)
            bf[nt] = *(const short8*)(Bs[cur] + (wc * 64 + nt * 16 + l16) * GBK + quad * 8);
#pragma unroll
        for (int mt = 0; mt < 4; mt++)
#pragma unroll
            for (int nt = 0; nt < 4; nt++)
                acc[mt][nt] = __builtin_amdgcn_mfma_f32_16x16x32_bf16(
                    af[mt], bf[nt], acc[mt][nt], 0, 0, 0);
        cur ^= 1;
    }

#pragma unroll
    for (int nt = 0; nt < 4; nt++) {
        int col = n0 + wc * 64 + nt * 16 + l16;
        float bv = bsel[col & 1023];
#pragma unroll
        for (int mt = 0; mt < 4; mt++) {
            int row = m0 + wr * 64 + mt * 16 + quad * 4;
#pragma unroll
            for (int r = 0; r < 4; r++)
                store_out(&C[(size_t)(row + r) * ldc + col], acc[mt][nt][r] + bv);
        }
    }
}

// ---------------------------------------------------------------------------
// gemm_bt64: 64x128 tile for the tail GEMM (512 blocks = 2 blocks/CU).
// XCD-chunked 8x8 rect swizzle (kept, measured win).
// ---------------------------------------------------------------------------
__global__ __launch_bounds__(256) void gemm_bt64(
    const u16* __restrict__ A, int lda,
    const u16* __restrict__ BT, int ldb,
    const float* __restrict__ bias,
    float* __restrict__ C, int ldc, int K) {
    __shared__ __align__(16) u16 As[2][64 * GBK];
    __shared__ __align__(16) u16 Bs[2][128 * GBK];

    const int tid = threadIdx.x;
    const int wave = tid >> 6, lane = tid & 63;
    const int quad = lane >> 4, l16 = lane & 15;

    int bx = blockIdx.x, by = blockIdx.y;
    if (gridDim.x == 8 && gridDim.y == 64) {
        const int wgid = blockIdx.x + blockIdx.y * 8;
        const int xcd = wgid & 7, t = wgid >> 3;      // t: 0..63
        bx = t & 7;
        by = (xcd << 3) + (t >> 3);
    }
    const int m0 = by * 64, n0 = bx * 128;

    f32x4 acc[4][2] = {};

    const int srow = tid >> 2;           // 0..63
    const int scol = (tid & 3) * 8;
    const u16* Ag0 = A + (size_t)(m0 + srow) * lda + scol;
    const u16* Bg0 = BT + (size_t)(n0 + srow) * ldb + scol;
    const u16* Bg1 = Bg0 + (size_t)64 * ldb;
    const int woff = wave << 9;

    async_ld16(Ag0, As[0] + woff);
    async_ld16(Bg0, Bs[0] + woff);
    async_ld16(Bg1, Bs[0] + woff + 64 * GBK);

    int cur = 0;
    for (int kb = 0; kb < K; kb += GBK) {
        __syncthreads();

        if (kb + GBK < K) {
            const int nxt = cur ^ 1;
            async_ld16(Ag0 + kb + GBK, As[nxt] + woff);
            async_ld16(Bg0 + kb + GBK, Bs[nxt] + woff);
            async_ld16(Bg1 + kb + GBK, Bs[nxt] + woff + 64 * GBK);
        }

        short8 af[4], bf[2];
#pragma unroll
        for (int mt = 0; mt < 4; mt++)
            af[mt] = *(const short8*)(As[cur] + (mt * 16 + l16) * GBK + quad * 8);
#pragma unroll
        for (int nt = 0; nt < 2; nt++)
            bf[nt] = *(const short8*)(Bs[cur] + (wave * 32 + nt * 16 + l16) * GBK + quad * 8);
#pragma unroll
        for (int mt = 0; mt < 4; mt++)
#pragma unroll
            for (int nt = 0; nt < 2; nt++)
                acc[mt][nt] = __builtin_amdgcn_mfma_f32_16x16x32_bf16(
                    af[mt], bf[nt], acc[mt][nt], 0, 0, 0);
        cur ^= 1;
    }

#pragma unroll
    for (int nt = 0; nt < 2; nt++) {
        int col = n0 + wave * 32 + nt * 16 + l16;
        float bv = bias[col & 1023];
#pragma unroll
        for (int mt = 0; mt < 4; mt++) {
            int row = m0 + mt * 16 + quad * 4;
#pragma unroll
            for (int r = 0; r < 4; r++)
                C[(size_t)(row + r) * ldc + col] = acc[mt][nt][r] + bv;
        }
    }
}

// ---------------------------------------------------------------------------
// Flash attention v10: v3+setprio (banked 55.9us) with
//  1) BKV=256, two-half compute: each 128-half runs the EXACT v3 body
//     (same st[2][8], same per-kv staging/read patterns) -> barrier drains
//     halve (32->16) and prefetch issue->use distance doubles (round 12
//     showed distance is the latency hider).  Cost: prefetch regs x2
//     (+32 VGPR, fine at 2 waves/SIMD), LDS 69KB (2 blocks/CU: 138<160).
//  2) XCD-cluster block swizzle (bijective, inverse-verified): the 16
//     q-blocks sharing one (h,bb) KV pair (512KB, L2-fits) land on 2 XCDs
//     instead of 8 -> KV reads become L2 hits.  Pure index remap.
// ---------------------------------------------------------------------------
#define SEQ 2048
#define BQT 128
#define BKV 256
#define LDK 72     // Ks row: 64 d + 8 pad
#define LDKV 264   // Vs row: 256 kk + 8 pad

__global__ __launch_bounds__(256) void attn(u16* __restrict__ QKV) {
    __shared__ __align__(16) u16 Ks[BKV * LDK];        // [kk][d]     36864 B
    __shared__ __align__(16) u16 Vs[64 * LDKV];        // [d][kvp]    33792 B

    const int tid = threadIdx.x;
    const int wave = tid >> 6, lane = tid & 63;
    const int quad = lane >> 4, l16 = lane & 15;

    // XCD-cluster swizzle: lin%8 ~ XCD.  h = (xcd>>1)|((t&3)<<2),
    // qb = ((xcd&1)<<3)|((t>>2)&7), bb = t>>5.  Bijective (inverse:
    // xcd = ((h&3)<<1)|(qb>>3); t = (h>>2)|((qb&7)<<2)|(bb<<5)).
    const int lin = blockIdx.x + blockIdx.y * 16 + blockIdx.z * 256;
    const int xcd = lin & 7, tswz = lin >> 3;
    const int h  = (xcd >> 1) | ((tswz & 3) << 2);
    const int qb = ((xcd & 1) << 3) | ((tswz >> 2) & 7);
    const int bb = tswz >> 5;
    const int q0 = qb * BQT;
    const size_t tok0 = (size_t)bb * SEQ;

    const u16* Qb = QKV + tok0 * 3072 + h * 64;
    const u16* Kb = QKV + tok0 * 3072 + 1024 + h * 64;
    const u16* Vb = QKV + tok0 * 3072 + 2048 + h * 64;

    const float cs = 0.18033688011112042f;  // (1/8) * log2(e)

    int qr[2];
    qr[0] = q0 + wave * 16 + l16;
    qr[1] = qr[0] + 64;
    short8 aq[2][2];
#pragma unroll
    for (int s = 0; s < 2; s++) {
        union { short8 v; u16 u[8]; uint32_t w[4]; } qa, qc;
        qa.v = *(const short8*)(Qb + (size_t)qr[s] * 3072 + quad * 8);
        qc.v = *(const short8*)(Qb + (size_t)qr[s] * 3072 + 32 + quad * 8);
#pragma unroll
        for (int j = 0; j < 4; j++) {
            qa.w[j] = pkbf(bf2f(qa.u[2 * j]) * cs, bf2f(qa.u[2 * j + 1]) * cs);
            qc.w[j] = pkbf(bf2f(qc.u[2 * j]) * cs, bf2f(qc.u[2 * j + 1]) * cs);
        }
        aq[s][0] = qa.v; aq[s][1] = qc.v;
    }

    f32x4 o[2][4] = {};
    f32x4 o_l[2] = {};   // MFMA row-sum accumulator (all 4 elems equal)

    const short8 vone = {16256, 16256, 16256, 16256,
                         16256, 16256, 16256, 16256};  // bf16 1.0 x8

    const int srow = tid >> 2;           // 0..63 (K rows srow + 64*i)
    const int scc = (tid & 3) * 16;      // 0/16/32/48
    const int pr = tid & 63;             // kv-pair id (pair0: 2pr, pair1: 128+2pr)
    const int dg = wave;

    const u16* kg = Kb + (size_t)srow * 3072 + scc;
    const u16* vg = Vb + (size_t)(2 * pr) * 3072 + dg * 16;

    // permuted kv slot (within each 32-block: kv=t*16+q*4+r -> q*8+t*4+r)
    const int kvb = 2 * pr;
    const int kvp = (kvb & 96) | (((kvb >> 2) & 3) << 3) |
                    (((kvb >> 4) & 1) << 2) | (kvb & 3);
    // pair1 (kvb+128): kvp + 128 (bit 7 passes through the block-id bits)

    uint4 kr[8];   // K rows srow+64i, 2 x 16B each
    uint4 vr[8];   // V pair0 rows 2pr,2pr+1 then pair1 rows +128
#pragma unroll
    for (int i = 0; i < 4; i++) {
        kr[2 * i]     = *(const uint4*)(kg + (size_t)(64 * i) * 3072);
        kr[2 * i + 1] = *(const uint4*)(kg + (size_t)(64 * i) * 3072 + 8);
    }
    vr[0] = *(const uint4*)(vg);
    vr[1] = *(const uint4*)(vg + 8);
    vr[2] = *(const uint4*)(vg + 3072);
    vr[3] = *(const uint4*)(vg + 3072 + 8);
    vr[4] = *(const uint4*)(vg + (size_t)128 * 3072);
    vr[5] = *(const uint4*)(vg + (size_t)128 * 3072 + 8);
    vr[6] = *(const uint4*)(vg + (size_t)129 * 3072);
    vr[7] = *(const uint4*)(vg + (size_t)129 * 3072 + 8);

    for (int j0 = 0; j0 < SEQ; j0 += BKV) {
        // stage K: 4 row-groups x 2 x 16B
#pragma unroll
        for (int i = 0; i < 4; i++) {
            *(uint4*)(Ks + (srow + 64 * i) * LDK + scc) = kr[2 * i];
            *(uint4*)(Ks + (srow + 64 * i) * LDK + scc + 8) = kr[2 * i + 1];
        }
        // stage V (transposed, permuted): 2 pairs x 16 d
        {
            union { uint4 v[2]; u16 u[16]; } a, b;
            a.v[0] = vr[0]; a.v[1] = vr[1]; b.v[0] = vr[2]; b.v[1] = vr[3];
#pragma unroll
            for (int j = 0; j < 16; j++) {
                uint32_t w = (uint32_t)a.u[j] | ((uint32_t)b.u[j] << 16);
                *(uint32_t*)(Vs + (dg * 16 + j) * LDKV + kvp) = w;
            }
            a.v[0] = vr[4]; a.v[1] = vr[5]; b.v[0] = vr[6]; b.v[1] = vr[7];
#pragma unroll
            for (int j = 0; j < 16; j++) {
                uint32_t w = (uint32_t)a.u[j] | ((uint32_t)b.u[j] << 16);
                *(uint32_t*)(Vs + (dg * 16 + j) * LDKV + kvp + 128) = w;
            }
        }
        __syncthreads();   // B1: staged tile visible

        if (j0 + BKV < SEQ) {
            const size_t off = (size_t)(j0 + BKV) * 3072;
#pragma unroll
            for (int i = 0; i < 4; i++) {
                kr[2 * i]     = *(const uint4*)(kg + off + (size_t)(64 * i) * 3072);
                kr[2 * i + 1] = *(const uint4*)(kg + off + (size_t)(64 * i) * 3072 + 8);
            }
            vr[0] = *(const uint4*)(vg + off);
            vr[1] = *(const uint4*)(vg + off + 8);
            vr[2] = *(const uint4*)(vg + off + 3072);
            vr[3] = *(const uint4*)(vg + off + 3072 + 8);
            vr[4] = *(const uint4*)(vg + off + (size_t)128 * 3072);
            vr[5] = *(const uint4*)(vg + off + (size_t)128 * 3072 + 8);
            vr[6] = *(const uint4*)(vg + off + (size_t)129 * 3072);
            vr[7] = *(const uint4*)(vg + off + (size_t)129 * 3072 + 8);
        }

        // two 128-kv halves, each the exact v3 body
#pragma unroll
        for (int hf = 0; hf < 2; hf++) {
            f32x4 st[2][8];
            __builtin_amdgcn_s_setprio(1);
#pragma unroll
            for (int kkt = 0; kkt < 8; kkt++) {
                f32x4 s0 = {}, s1 = {};
#pragma unroll
                for (int k2 = 0; k2 < 2; k2++) {
                    short8 ak = *(const short8*)(Ks + (hf * 128 + kkt * 16 + l16) * LDK +
                                                 k2 * 32 + quad * 8);
                    s0 = __builtin_amdgcn_mfma_f32_16x16x32_bf16(ak, aq[0][k2], s0, 0, 0, 0);
                    s1 = __builtin_amdgcn_mfma_f32_16x16x32_bf16(ak, aq[1][k2], s1, 0, 0, 0);
                }
                st[0][kkt] = s0; st[1][kkt] = s1;
            }
            __builtin_amdgcn_s_setprio(0);

#pragma unroll
            for (int s = 0; s < 2; s++)
#pragma unroll
                for (int kkt = 0; kkt < 8; kkt++)
#pragma unroll
                    for (int r = 0; r < 4; r++)
                        st[s][kkt][r] = __builtin_amdgcn_exp2f(st[s][kkt][r]);

            __builtin_amdgcn_s_setprio(1);
#pragma unroll
            for (int tt = 0; tt < 4; tt++) {
                union { uint32_t w[4]; short8 v; } bp0, bp1;
                bp0.w[0] = pkbf(st[0][2 * tt][0], st[0][2 * tt][1]);
                bp0.w[1] = pkbf(st[0][2 * tt][2], st[0][2 * tt][3]);
                bp0.w[2] = pkbf(st[0][2 * tt + 1][0], st[0][2 * tt + 1][1]);
                bp0.w[3] = pkbf(st[0][2 * tt + 1][2], st[0][2 * tt + 1][3]);
                bp1.w[0] = pkbf(st[1][2 * tt][0], st[1][2 * tt][1]);
                bp1.w[1] = pkbf(st[1][2 * tt][2], st[1][2 * tt][3]);
                bp1.w[2] = pkbf(st[1][2 * tt + 1][0], st[1][2 * tt + 1][1]);
                bp1.w[3] = pkbf(st[1][2 * tt + 1][2], st[1][2 * tt + 1][3]);

                o_l[0] = __builtin_amdgcn_mfma_f32_16x16x32_bf16(vone, bp0.v, o_l[0], 0, 0, 0);
                o_l[1] = __builtin_amdgcn_mfma_f32_16x16x32_bf16(vone, bp1.v, o_l[1], 0, 0, 0);
#pragma unroll
                for (int dt = 0; dt < 4; dt++) {
                    short8 av = *(const short8*)(Vs + (dt * 16 + l16) * LDKV +
                                                 hf * 128 + tt * 32 + quad * 8);
                    o[0][dt] = __builtin_amdgcn_mfma_f32_16x16x32_bf16(av, bp0.v, o[0][dt], 0, 0, 0);
                    o[1][dt] = __builtin_amdgcn_mfma_f32_16x16x32_bf16(av, bp1.v, o[1][dt], 0, 0, 0);
                }
            }
            __builtin_amdgcn_s_setprio(0);
        }

        __syncthreads();   // B2: Ks/Vs reads done before next staging
    }

#pragma unroll
    for (int s = 0; s < 2; s++) {
        const float inv_l = 1.0f / o_l[s][0];
        u16* orow = QKV + (tok0 + qr[s]) * 3072 + h * 64;
#pragma unroll
        for (int dt = 0; dt < 4; dt++) {
            uint32_t w0 = pkbf(o[s][dt][0] * inv_l, o[s][dt][1] * inv_l);
            uint32_t w1 = pkbf(o[s][dt][2] * inv_l, o[s][dt][3] * inv_l);
            uint2 w = {w0, w1};
            *(uint2*)(orow + dt * 16 + quad * 4) = w;
        }
    }
}

// ---------------------------------------------------------------------------
extern "C" void kernel_launch(void* const* d_in, const int* in_sizes, int n_in,
                              void* d_out, int out_size, void* d_ws, size_t ws_size,
                              hipStream_t stream) {
    const float* x  = (const float*)d_in[0];
    const float* wq = (const float*)d_in[1];
    const float* bq = (const float*)d_in[2];
    const float* wk = (const float*)d_in[3];
    const float* bk = (const float*)d_in[4];
    const float* wv = (const float*)d_in[5];
    const float* bv = (const float*)d_in[6];
    const float* wo = (const float*)d_in[7];
    const float* bo = (const float*)d_in[8];
    (void)in_sizes; (void)n_in; (void)out_size;

    u16* QKV = (u16*)d_ws;                              // [4096][3072] bf16, 24 MB
    u16* wT  = QKV + (size_t)4096 * 3072;               // [3][1024][1024] bf16, 6 MB
    u16* xb  = wT + (size_t)3 * 1024 * 1024;            // [4096][1024] bf16, 8 MB
    u16* woT = xb;                                      // fallback: reuses xb after gemm1
    u16* woT2 = xb + (size_t)4096 * 1024;               // fused: own 2 MB region

    const size_t need = ((size_t)4096 * 3072 + (size_t)4 * 1024 * 1024 +
                         (size_t)4096 * 1024) * sizeof(u16);
    const bool fused = (ws_size >= need);

    if (fused) {
        prep<<<dim3(32, 32, 6), dim3(32, 8), 0, stream>>>(x, wq, wk, wv, wo,
                                                          xb, wT, woT2);
        gemm_bt<u16><<<dim3(24, 32), 256, 0, stream>>>(xb, 1024, wT, 1024,
                                                       bq, bk, bv, QKV, 3072, 1024);
        attn<<<dim3(16, 16, 2), 256, 0, stream>>>(QKV);
        gemm_bt64<<<dim3(8, 64), 256, 0, stream>>>(QKV, 3072, woT2, 1024, bo,
                                                   (float*)d_out, 1024, 1024);
    } else {
        prep<<<dim3(32, 32, 5), dim3(32, 8), 0, stream>>>(x, wq, wk, wv, wo,
                                                          xb, wT, woT2);
        gemm_bt<u16><<<dim3(24, 32), 256, 0, stream>>>(xb, 1024, wT, 1024,
                                                       bq, bk, bv, QKV, 3072, 1024);
        transpose1<<<dim3(32, 32), dim3(32, 8), 0, stream>>>(wo, woT);
        attn<<<dim3(16, 16, 2), 256, 0, stream>>>(QKV);
        gemm_bt64<<<dim3(8, 64), 256, 0, stream>>>(QKV, 3072, woT, 1024, bo,
                                                   (float*)d_out, 1024, 1024);
    }
}

// Round 15
// 190.122 us; speedup vs baseline: 1.2047x; 1.2047x over previous
//
#include <hip/hip_runtime.h>
#include <hip/hip_bf16.h>
#include <stdint.h>

typedef unsigned short u16;
typedef __attribute__((ext_vector_type(8))) short short8;
typedef __attribute__((ext_vector_type(4))) float f32x4;

__device__ __forceinline__ float bf2f(u16 u) {
    union { uint32_t u; float f; } v; v.u = ((uint32_t)u) << 16; return v.f;
}
__device__ __forceinline__ u16 f2bf(float f) {
    union { float f; uint32_t u; } v; v.f = f;
    uint32_t r = (v.u + 0x7fffu + ((v.u >> 16) & 1u)) >> 16;
    return (u16)r;
}
__device__ __forceinline__ uint32_t pkbf(float a, float b) {
    union { __hip_bfloat162 h; uint32_t w; } u;
    u.h = __float22bfloat162_rn(float2{a, b});
    return u.w;
}
__device__ __forceinline__ void store_out(u16* p, float v) { *p = f2bf(v); }
__device__ __forceinline__ void store_out(float* p, float v) { *p = v; }

__device__ __forceinline__ void async_ld16(const u16* g, u16* l) {
    __builtin_amdgcn_global_load_lds(
        (const __attribute__((address_space(1))) void*)g,
        (__attribute__((address_space(3))) void*)l, 16, 0, 0);
}

// ---------------------------------------------------------------------------
// prep: z in {0,1,2} -> transpose wq/wk/wv fp32 -> bf16 wT[z];
//       z in {3,4}   -> cvt x fp32 -> bf16 (chunk z-3 of 2);
//       z == 5       -> transpose wo -> woT (fused path only).
// ---------------------------------------------------------------------------
__global__ void prep(const float* __restrict__ x,
                     const float* __restrict__ w0, const float* __restrict__ w1,
                     const float* __restrict__ w2, const float* __restrict__ w3,
                     u16* __restrict__ xb, u16* __restrict__ wT,
                     u16* __restrict__ woT) {
    const int z = blockIdx.z;
    __shared__ u16 tile[32][33];
    if (z == 3 || z == 4) {
        int blk = (z - 3) * 1024 + blockIdx.y * 32 + blockIdx.x;
        int tid = threadIdx.y * 32 + threadIdx.x;
        int i = (blk * 256 + tid) * 8;
        float4 a = *(const float4*)(x + i);
        float4 b = *(const float4*)(x + i + 4);
        union { uint32_t w[4]; uint4 v; } o;
        o.w[0] = pkbf(a.x, a.y); o.w[1] = pkbf(a.z, a.w);
        o.w[2] = pkbf(b.x, b.y); o.w[3] = pkbf(b.z, b.w);
        *(uint4*)(xb + i) = o.v;
        return;
    }
    const float* in = (z == 0) ? w0 : (z == 1) ? w1 : (z == 2) ? w2 : w3;
    u16* o = (z < 3) ? (wT + (size_t)z * 1024 * 1024) : woT;
    int xx = blockIdx.x * 32 + threadIdx.x;
    int y0 = blockIdx.y * 32;
#pragma unroll
    for (int j = threadIdx.y; j < 32; j += 8)
        tile[j][threadIdx.x] = f2bf(in[(size_t)(y0 + j) * 1024 + xx]);
    __syncthreads();
    int ox = blockIdx.y * 32 + threadIdx.x;
    int oy0 = blockIdx.x * 32;
#pragma unroll
    for (int j = threadIdx.y; j < 32; j += 8)
        o[(size_t)(oy0 + j) * 1024 + ox] = tile[threadIdx.x][j];
}

// single-plane weight transpose (fallback path when workspace is tight)
__global__ void transpose1(const float* __restrict__ w, u16* __restrict__ out) {
    __shared__ u16 tile[32][33];
    int x = blockIdx.x * 32 + threadIdx.x;
    int y0 = blockIdx.y * 32;
#pragma unroll
    for (int j = threadIdx.y; j < 32; j += 8)
        tile[j][threadIdx.x] = f2bf(w[(size_t)(y0 + j) * 1024 + x]);
    __syncthreads();
    int ox = blockIdx.y * 32 + threadIdx.x;
    int oy0 = blockIdx.x * 32;
#pragma unroll
    for (int j = threadIdx.y; j < 32; j += 8)
        out[(size_t)(oy0 + j) * 1024 + ox] = tile[threadIdx.x][j];
}

// ---------------------------------------------------------------------------
// GEMM (B^T bf16): double-buffered async-LDS staging, ONE barrier per K-iter.
// 128x128 tile, 4 waves in 2x2.  XCD-chunked 2D block swizzle (measured win).
// ---------------------------------------------------------------------------
#define GBM 128
#define GBN 128
#define GBK 32

template <typename OutT>
__global__ __launch_bounds__(256) void gemm_bt(
    const u16* __restrict__ A, int lda,
    const u16* __restrict__ BT, int ldb,
    const float* __restrict__ bias0, const float* __restrict__ bias1,
    const float* __restrict__ bias2,
    OutT* __restrict__ C, int ldc, int K) {
    __shared__ __align__(16) u16 As[2][GBM * GBK];
    __shared__ __align__(16) u16 Bs[2][GBN * GBK];

    const int tid = threadIdx.x;
    const int wave = tid >> 6, lane = tid & 63;
    const int quad = lane >> 4, l16 = lane & 15;
    const int wr = wave >> 1, wc = wave & 1;

    int bx = blockIdx.x, by = blockIdx.y;
    if (gridDim.x == 24 && gridDim.y == 32) {
        const int wgid = blockIdx.x + blockIdx.y * 24;
        const int xcd = wgid & 7, t = wgid >> 3;      // t: 0..95
        bx = (xcd & 1) * 12 + t % 12;
        by = (xcd >> 1) * 8 + t / 12;
    }
    const int m0 = by * GBM, n0 = bx * GBN;

    const int seg = n0 >> 10;
    const float* bsel = (seg == 0) ? bias0 : (seg == 1) ? bias1 : bias2;

    f32x4 acc[4][4] = {};

    const int srow = tid >> 2;
    const int scol = (tid & 3) * 8;
    const u16* Ag0 = A + (size_t)(m0 + srow) * lda + scol;
    const u16* Ag1 = Ag0 + (size_t)64 * lda;
    const u16* Bg0 = BT + (size_t)(n0 + srow) * ldb + scol;
    const u16* Bg1 = Bg0 + (size_t)64 * ldb;
    const int woff = wave << 9;

    async_ld16(Ag0, As[0] + woff);
    async_ld16(Ag1, As[0] + woff + 64 * GBK);
    async_ld16(Bg0, Bs[0] + woff);
    async_ld16(Bg1, Bs[0] + woff + 64 * GBK);

    int cur = 0;
    for (int kb = 0; kb < K; kb += GBK) {
        __syncthreads();

        if (kb + GBK < K) {
            const int nxt = cur ^ 1;
            async_ld16(Ag0 + kb + GBK, As[nxt] + woff);
            async_ld16(Ag1 + kb + GBK, As[nxt] + woff + 64 * GBK);
            async_ld16(Bg0 + kb + GBK, Bs[nxt] + woff);
            async_ld16(Bg1 + kb + GBK, Bs[nxt] + woff + 64 * GBK);
        }

        short8 af[4], bf[4];
#pragma unroll
        for (int mt = 0; mt < 4; mt++)
            af[mt] = *(const short8*)(As[cur] + (wr * 64 + mt * 16 + l16) * GBK + quad * 8);
#pragma unroll
        for (int nt = 0; nt < 4; nt++)
            bf[nt] = *(const short8*)(Bs[cur] + (wc * 64 + nt * 16 + l16) * GBK + quad * 8);
#pragma unroll
        for (int mt = 0; mt < 4; mt++)
#pragma unroll
            for (int nt = 0; nt < 4; nt++)
                acc[mt][nt] = __builtin_amdgcn_mfma_f32_16x16x32_bf16(
                    af[mt], bf[nt], acc[mt][nt], 0, 0, 0);
        cur ^= 1;
    }

#pragma unroll
    for (int nt = 0; nt < 4; nt++) {
        int col = n0 + wc * 64 + nt * 16 + l16;
        float bv = bsel[col & 1023];
#pragma unroll
        for (int mt = 0; mt < 4; mt++) {
            int row = m0 + wr * 64 + mt * 16 + quad * 4;
#pragma unroll
            for (int r = 0; r < 4; r++)
                store_out(&C[(size_t)(row + r) * ldc + col], acc[mt][nt][r] + bv);
        }
    }
}

// ---------------------------------------------------------------------------
// gemm_bt64: 64x128 tile for the tail GEMM (512 blocks = 2 blocks/CU).
// XCD-chunked 8x8 rect swizzle (kept, measured win).
// ---------------------------------------------------------------------------
__global__ __launch_bounds__(256) void gemm_bt64(
    const u16* __restrict__ A, int lda,
    const u16* __restrict__ BT, int ldb,
    const float* __restrict__ bias,
    float* __restrict__ C, int ldc, int K) {
    __shared__ __align__(16) u16 As[2][64 * GBK];
    __shared__ __align__(16) u16 Bs[2][128 * GBK];

    const int tid = threadIdx.x;
    const int wave = tid >> 6, lane = tid & 63;
    const int quad = lane >> 4, l16 = lane & 15;

    int bx = blockIdx.x, by = blockIdx.y;
    if (gridDim.x == 8 && gridDim.y == 64) {
        const int wgid = blockIdx.x + blockIdx.y * 8;
        const int xcd = wgid & 7, t = wgid >> 3;      // t: 0..63
        bx = t & 7;
        by = (xcd << 3) + (t >> 3);
    }
    const int m0 = by * 64, n0 = bx * 128;

    f32x4 acc[4][2] = {};

    const int srow = tid >> 2;           // 0..63
    const int scol = (tid & 3) * 8;
    const u16* Ag0 = A + (size_t)(m0 + srow) * lda + scol;
    const u16* Bg0 = BT + (size_t)(n0 + srow) * ldb + scol;
    const u16* Bg1 = Bg0 + (size_t)64 * ldb;
    const int woff = wave << 9;

    async_ld16(Ag0, As[0] + woff);
    async_ld16(Bg0, Bs[0] + woff);
    async_ld16(Bg1, Bs[0] + woff + 64 * GBK);

    int cur = 0;
    for (int kb = 0; kb < K; kb += GBK) {
        __syncthreads();

        if (kb + GBK < K) {
            const int nxt = cur ^ 1;
            async_ld16(Ag0 + kb + GBK, As[nxt] + woff);
            async_ld16(Bg0 + kb + GBK, Bs[nxt] + woff);
            async_ld16(Bg1 + kb + GBK, Bs[nxt] + woff + 64 * GBK);
        }

        short8 af[4], bf[2];
#pragma unroll
        for (int mt = 0; mt < 4; mt++)
            af[mt] = *(const short8*)(As[cur] + (mt * 16 + l16) * GBK + quad * 8);
#pragma unroll
        for (int nt = 0; nt < 2; nt++)
            bf[nt] = *(const short8*)(Bs[cur] + (wave * 32 + nt * 16 + l16) * GBK + quad * 8);
#pragma unroll
        for (int mt = 0; mt < 4; mt++)
#pragma unroll
            for (int nt = 0; nt < 2; nt++)
                acc[mt][nt] = __builtin_amdgcn_mfma_f32_16x16x32_bf16(
                    af[mt], bf[nt], acc[mt][nt], 0, 0, 0);
        cur ^= 1;
    }

#pragma unroll
    for (int nt = 0; nt < 2; nt++) {
        int col = n0 + wave * 32 + nt * 16 + l16;
        float bv = bias[col & 1023];
#pragma unroll
        for (int mt = 0; mt < 4; mt++) {
            int row = m0 + mt * 16 + quad * 4;
#pragma unroll
            for (int r = 0; r < 4; r++)
                C[(size_t)(row + r) * ldc + col] = acc[mt][nt][r] + bv;
        }
    }
}

// ---------------------------------------------------------------------------
// Flash attention v11: round-13 banked body (v3+setprio, BKV=128, 55.9us)
// plus ONLY the XCD-cluster block swizzle from round 14.  Round 14's BKV=256
// doubled prefetch regs past the allocator's 128 target -> ~90MB scratch
// spill (WRITE_SIZE 8.2->90MB), retired.  But its swizzle cut FETCH_SIZE
// 69.7->28.8MB (KV/Q reads became L2 hits) -- kept here as the single
// variable.  Mapping (bijective, inverse-verified): lin%8 ~ XCD;
// h=(xcd>>1)|((t&3)<<2), qb=((xcd&1)<<3)|((t>>2)&7), bb=t>>5 -- the 16
// q-blocks sharing one (h,bb) 512KB KV pair land on 2 XCDs instead of 8.
// ---------------------------------------------------------------------------
#define SEQ 2048
#define BQT 128
#define BKV 128
#define LDK 72     // Ks row: 64 d + 8 pad
#define LDKV 136   // Vs row: 128 kk + 8 pad

__global__ __launch_bounds__(256) void attn(u16* __restrict__ QKV) {
    __shared__ __align__(16) u16 Ks[BKV * LDK];        // [kk][d]
    __shared__ __align__(16) u16 Vs[64 * LDKV];        // [d][kvp] (transposed, permuted)

    const int tid = threadIdx.x;
    const int wave = tid >> 6, lane = tid & 63;
    const int quad = lane >> 4, l16 = lane & 15;

    // XCD-cluster swizzle (sole change vs round-13 attn)
    const int lin = blockIdx.x + blockIdx.y * 16 + blockIdx.z * 256;
    const int xcd = lin & 7, tswz = lin >> 3;
    const int h  = (xcd >> 1) | ((tswz & 3) << 2);
    const int qb = ((xcd & 1) << 3) | ((tswz >> 2) & 7);
    const int bb = tswz >> 5;
    const int q0 = qb * BQT;
    const size_t tok0 = (size_t)bb * SEQ;

    const u16* Qb = QKV + tok0 * 3072 + h * 64;
    const u16* Kb = QKV + tok0 * 3072 + 1024 + h * 64;
    const u16* Vb = QKV + tok0 * 3072 + 2048 + h * 64;

    const float cs = 0.18033688011112042f;  // (1/8) * log2(e)

    int qr[2];
    qr[0] = q0 + wave * 16 + l16;
    qr[1] = qr[0] + 64;
    short8 aq[2][2];
#pragma unroll
    for (int s = 0; s < 2; s++) {
        union { short8 v; u16 u[8]; uint32_t w[4]; } qa, qb_;
        qa.v = *(const short8*)(Qb + (size_t)qr[s] * 3072 + quad * 8);
        qb_.v = *(const short8*)(Qb + (size_t)qr[s] * 3072 + 32 + quad * 8);
#pragma unroll
        for (int j = 0; j < 4; j++) {
            qa.w[j] = pkbf(bf2f(qa.u[2 * j]) * cs, bf2f(qa.u[2 * j + 1]) * cs);
            qb_.w[j] = pkbf(bf2f(qb_.u[2 * j]) * cs, bf2f(qb_.u[2 * j + 1]) * cs);
        }
        aq[s][0] = qa.v; aq[s][1] = qb_.v;
    }

    f32x4 o[2][4] = {};
    f32x4 o_l[2] = {};   // MFMA row-sum accumulator (all 4 elems equal)

    const short8 vone = {16256, 16256, 16256, 16256,
                         16256, 16256, 16256, 16256};  // bf16 1.0 x8

    const int srow = tid >> 2;           // 0..63
    const int scc = (tid & 3) * 16;      // 0/16/32/48
    const int pr = tid & 63;
    const int dg = wave;

    const u16* kg = Kb + (size_t)srow * 3072 + scc;
    const u16* vg = Vb + (size_t)(2 * pr) * 3072 + dg * 16;

    // permuted kv slot for this thread's pair (pair stays adjacent & aligned)
    const int kvb = 2 * pr;
    const int kvp = (kvb & 96) | (((kvb >> 2) & 3) << 3) |
                    (((kvb >> 4) & 1) << 2) | (kvb & 3);

    uint4 k0r = *(const uint4*)(kg);
    uint4 k1r = *(const uint4*)(kg + 8);
    uint4 k2r = *(const uint4*)(kg + (size_t)64 * 3072);
    uint4 k3r = *(const uint4*)(kg + (size_t)64 * 3072 + 8);
    uint4 va0 = *(const uint4*)(vg);
    uint4 va1 = *(const uint4*)(vg + 8);
    uint4 vb0 = *(const uint4*)(vg + 3072);
    uint4 vb1 = *(const uint4*)(vg + 3072 + 8);

    for (int j0 = 0; j0 < SEQ; j0 += BKV) {
        *(uint4*)(Ks + srow * LDK + scc) = k0r;
        *(uint4*)(Ks + srow * LDK + scc + 8) = k1r;
        *(uint4*)(Ks + (srow + 64) * LDK + scc) = k2r;
        *(uint4*)(Ks + (srow + 64) * LDK + scc + 8) = k3r;
        {
            union { uint4 v[2]; u16 u[16]; } a, b;
            a.v[0] = va0; a.v[1] = va1; b.v[0] = vb0; b.v[1] = vb1;
#pragma unroll
            for (int j = 0; j < 16; j++) {
                uint32_t w = (uint32_t)a.u[j] | ((uint32_t)b.u[j] << 16);
                *(uint32_t*)(Vs + (dg * 16 + j) * LDKV + kvp) = w;
            }
        }
        __syncthreads();   // B1: staged tile visible

        if (j0 + BKV < SEQ) {
            size_t off = (size_t)(j0 + BKV) * 3072;
            k0r = *(const uint4*)(kg + off);
            k1r = *(const uint4*)(kg + off + 8);
            k2r = *(const uint4*)(kg + off + (size_t)64 * 3072);
            k3r = *(const uint4*)(kg + off + (size_t)64 * 3072 + 8);
            va0 = *(const uint4*)(vg + off);
            va1 = *(const uint4*)(vg + off + 8);
            vb0 = *(const uint4*)(vg + off + 3072);
            vb1 = *(const uint4*)(vg + off + 3072 + 8);
        }

        f32x4 st[2][8];
        __builtin_amdgcn_s_setprio(1);
#pragma unroll
        for (int kkt = 0; kkt < 8; kkt++) {
            f32x4 s0 = {}, s1 = {};
#pragma unroll
            for (int k2 = 0; k2 < 2; k2++) {
                short8 ak = *(const short8*)(Ks + (kkt * 16 + l16) * LDK + k2 * 32 + quad * 8);
                s0 = __builtin_amdgcn_mfma_f32_16x16x32_bf16(ak, aq[0][k2], s0, 0, 0, 0);
                s1 = __builtin_amdgcn_mfma_f32_16x16x32_bf16(ak, aq[1][k2], s1, 0, 0, 0);
            }
            st[0][kkt] = s0; st[1][kkt] = s1;
        }
        __builtin_amdgcn_s_setprio(0);

        // exp2 only; row-sum is folded into PV via the ones-fragment MFMA
#pragma unroll
        for (int s = 0; s < 2; s++)
#pragma unroll
            for (int kkt = 0; kkt < 8; kkt++)
#pragma unroll
                for (int r = 0; r < 4; r++)
                    st[s][kkt][r] = __builtin_amdgcn_exp2f(st[s][kkt][r]);

        // PV: four 32-kv tiles, full-rate 16x16x32 (+ l-sum MFMA per tile)
        __builtin_amdgcn_s_setprio(1);
#pragma unroll
        for (int tt = 0; tt < 4; tt++) {
            union { uint32_t w[4]; short8 v; } bp0, bp1;
            bp0.w[0] = pkbf(st[0][2 * tt][0], st[0][2 * tt][1]);
            bp0.w[1] = pkbf(st[0][2 * tt][2], st[0][2 * tt][3]);
            bp0.w[2] = pkbf(st[0][2 * tt + 1][0], st[0][2 * tt + 1][1]);
            bp0.w[3] = pkbf(st[0][2 * tt + 1][2], st[0][2 * tt + 1][3]);
            bp1.w[0] = pkbf(st[1][2 * tt][0], st[1][2 * tt][1]);
            bp1.w[1] = pkbf(st[1][2 * tt][2], st[1][2 * tt][3]);
            bp1.w[2] = pkbf(st[1][2 * tt + 1][0], st[1][2 * tt + 1][1]);
            bp1.w[3] = pkbf(st[1][2 * tt + 1][2], st[1][2 * tt + 1][3]);

            o_l[0] = __builtin_amdgcn_mfma_f32_16x16x32_bf16(vone, bp0.v, o_l[0], 0, 0, 0);
            o_l[1] = __builtin_amdgcn_mfma_f32_16x16x32_bf16(vone, bp1.v, o_l[1], 0, 0, 0);
#pragma unroll
            for (int dt = 0; dt < 4; dt++) {
                short8 av = *(const short8*)(Vs + (dt * 16 + l16) * LDKV +
                                             tt * 32 + quad * 8);
                o[0][dt] = __builtin_amdgcn_mfma_f32_16x16x32_bf16(av, bp0.v, o[0][dt], 0, 0, 0);
                o[1][dt] = __builtin_amdgcn_mfma_f32_16x16x32_bf16(av, bp1.v, o[1][dt], 0, 0, 0);
            }
        }
        __builtin_amdgcn_s_setprio(0);

        __syncthreads();   // B2: Ks/Vs reads done before next staging
    }

#pragma unroll
    for (int s = 0; s < 2; s++) {
        const float inv_l = 1.0f / o_l[s][0];
        u16* orow = QKV + (tok0 + qr[s]) * 3072 + h * 64;
#pragma unroll
        for (int dt = 0; dt < 4; dt++) {
            uint32_t w0 = pkbf(o[s][dt][0] * inv_l, o[s][dt][1] * inv_l);
            uint32_t w1 = pkbf(o[s][dt][2] * inv_l, o[s][dt][3] * inv_l);
            uint2 w = {w0, w1};
            *(uint2*)(orow + dt * 16 + quad * 4) = w;
        }
    }
}

// ---------------------------------------------------------------------------
extern "C" void kernel_launch(void* const* d_in, const int* in_sizes, int n_in,
                              void* d_out, int out_size, void* d_ws, size_t ws_size,
                              hipStream_t stream) {
    const float* x  = (const float*)d_in[0];
    const float* wq = (const float*)d_in[1];
    const float* bq = (const float*)d_in[2];
    const float* wk = (const float*)d_in[3];
    const float* bk = (const float*)d_in[4];
    const float* wv = (const float*)d_in[5];
    const float* bv = (const float*)d_in[6];
    const float* wo = (const float*)d_in[7];
    const float* bo = (const float*)d_in[8];
    (void)in_sizes; (void)n_in; (void)out_size;

    u16* QKV = (u16*)d_ws;                              // [4096][3072] bf16, 24 MB
    u16* wT  = QKV + (size_t)4096 * 3072;               // [3][1024][1024] bf16, 6 MB
    u16* xb  = wT + (size_t)3 * 1024 * 1024;            // [4096][1024] bf16, 8 MB
    u16* woT = xb;                                      // fallback: reuses xb after gemm1
    u16* woT2 = xb + (size_t)4096 * 1024;               // fused: own 2 MB region

    const size_t need = ((size_t)4096 * 3072 + (size_t)4 * 1024 * 1024 +
                         (size_t)4096 * 1024) * sizeof(u16);
    const bool fused = (ws_size >= need);

    if (fused) {
        prep<<<dim3(32, 32, 6), dim3(32, 8), 0, stream>>>(x, wq, wk, wv, wo,
                                                          xb, wT, woT2);
        gemm_bt<u16><<<dim3(24, 32), 256, 0, stream>>>(xb, 1024, wT, 1024,
                                                       bq, bk, bv, QKV, 3072, 1024);
        attn<<<dim3(16, 16, 2), 256, 0, stream>>>(QKV);
        gemm_bt64<<<dim3(8, 64), 256, 0, stream>>>(QKV, 3072, woT2, 1024, bo,
                                                   (float*)d_out, 1024, 1024);
    } else {
        prep<<<dim3(32, 32, 5), dim3(32, 8), 0, stream>>>(x, wq, wk, wv, wo,
                                                          xb, wT, woT2);
        gemm_bt<u16><<<dim3(24, 32), 256, 0, stream>>>(xb, 1024, wT, 1024,
                                                       bq, bk, bv, QKV, 3072, 1024);
        transpose1<<<dim3(32, 32), dim3(32, 8), 0, stream>>>(wo, woT);
        attn<<<dim3(16, 16, 2), 256, 0, stream>>>(QKV);
        gemm_bt64<<<dim3(8, 64), 256, 0, stream>>>(QKV, 3072, woT, 1024, bo,
                                                   (float*)d_out, 1024, 1024);
    }
}